// Round 2
// baseline (426.488 us; speedup 1.0000x reference)
//
#include <hip/hip_runtime.h>

// RetinaNet post-processor, MI355X. Round 2.
// N=2, A=9, C=80, H=100, W=152. PRE_NMS_TOP_N=1000, POST_TOP_N=100.
//
//  K1 scan:   grid-stride streaming pass over box_cls (87.5MB), no barriers.
//             Candidates = logits x > 2.0 (rank-1000 logit ~3.48; ~15K/image).
//             Wave-aggregated compaction (ballot + leader atomic) on rare path.
//             2048-bin histogram of x in [2,10).
//  K2 selfin: per-image block (1024 thr): exact bin cutoff (suffix>=1000),
//             compact survivors, bitonic sort 2048 keys in LDS
//             (key = sigmoid_bits<<32 | ~idx == jax top_k stable order),
//             decode top-1000 boxes, single-wave greedy class-offset NMS with
//             early-exit at 100 keeps, emit.

#define W_    152
#define H_    100
#define A_    9
#define C_    80
#define HW_   (H_*W_)            // 15200
#define PER_IMG  (A_*C_*HW_)     // 10944000
#define PER_IMG4 (PER_IMG/4)     // 2736000
#define NBIN  2048
#define BIGCAP 24576
#define SORTN 2048
#define STATIC_X 2.0f
#define CLIPV 4.135166556742356f  // log(1000/16)

#define NB_SCAN 640
#define TPB     256
#define SSTRIDE (NB_SCAN*TPB)    // 163840 threads per image

// ws layout (bytes):
#define OFF_HIST   0                  // 2 x 2048 u32 = 16384
#define OFF_BIGCNT 16384              // 2 u32
#define OFF_BIG    16640              // 2 x BIGCAP x float2

__device__ __forceinline__ void scan_process(
    float4 vv, int t4, int lane,
    unsigned int* __restrict__ hn,
    unsigned int* __restrict__ bigcnt_n,
    float2* __restrict__ big_n) {
  const bool q0 = vv.x > STATIC_X, q1 = vv.y > STATIC_X,
             q2 = vv.z > STATIC_X, q3 = vv.w > STATIC_X;
  if (__any(q0 || q1 || q2 || q3)) {
    // index math only on the rare path
    const int f0  = t4 * 4;
    const int ac  = f0 / HW_;
    const int rem = f0 - ac * HW_;
    const int h   = rem / W_;
    const int w0  = rem - h * W_;
    const int a   = ac / C_;
    const int c   = ac - a * C_;
    const int idx0 = ((h * W_ + w0) * A_ + a) * C_ + c;   // +720 per elem step
    const float xs[4] = {vv.x, vv.y, vv.z, vv.w};
#pragma unroll
    for (int j = 0; j < 4; ++j) {
      const float x = xs[j];
      const bool p = x > STATIC_X;
      const unsigned long long mb = __ballot(p);
      if (mb) {
        if (p) {
          int b = (int)((x - STATIC_X) * 256.0f); if (b > NBIN - 1) b = NBIN - 1;
          atomicAdd(&hn[b], 1u);
        }
        const int leader = __ffsll(mb) - 1;
        unsigned bbase = 0;
        if (lane == leader) bbase = atomicAdd(bigcnt_n, (unsigned)__popcll(mb));
        bbase = (unsigned)__shfl((int)bbase, leader);
        if (p) {
          unsigned pos = bbase + (unsigned)__popcll(mb & ((1ull << lane) - 1ull));
          if (pos < BIGCAP)
            big_n[pos] = make_float2(x, __uint_as_float((unsigned)(idx0 + j * 720)));
        }
      }
    }
  }
}

__global__ __launch_bounds__(TPB) void scan_kernel(
    const float* __restrict__ cls,
    unsigned int* __restrict__ hist,
    unsigned int* __restrict__ bigcount,
    float2* __restrict__ big) {
  const int n = blockIdx.y;
  const float4* __restrict__ in = reinterpret_cast<const float4*>(cls) + (size_t)n * PER_IMG4;
  unsigned int* __restrict__ hn = hist + n * NBIN;
  unsigned int* __restrict__ bigcnt_n = bigcount + n;
  float2* __restrict__ big_n = big + (size_t)n * BIGCAP;
  const int gid  = blockIdx.x * TPB + threadIdx.x;
  const int lane = threadIdx.x & 63;

  for (int base = gid; base < PER_IMG4; base += 4 * SSTRIDE) {
    // issue up to 4 independent loads before any processing
    const int t0 = base;
    const int t1 = base + SSTRIDE;
    const int t2 = base + 2 * SSTRIDE;
    const int t3 = base + 3 * SSTRIDE;
    float4 v0 = make_float4(-100.f, -100.f, -100.f, -100.f), v1 = v0, v2 = v0, v3 = v0;
    v0 = in[t0];
    if (t1 < PER_IMG4) v1 = in[t1];
    if (t2 < PER_IMG4) v2 = in[t2];
    if (t3 < PER_IMG4) v3 = in[t3];
    scan_process(v0, t0, lane, hn, bigcnt_n, big_n);
    scan_process(v1, t1, lane, hn, bigcnt_n, big_n);
    scan_process(v2, t2, lane, hn, bigcnt_n, big_n);
    scan_process(v3, t3, lane, hn, bigcnt_n, big_n);
  }
}

__global__ __launch_bounds__(1024) void selfin_kernel(
    const unsigned int* __restrict__ hist,
    const unsigned int* __restrict__ bigcount,
    const float2* __restrict__ big,
    const float* __restrict__ reg, const float* __restrict__ anchors,
    float* __restrict__ out) {
  const int n = blockIdx.x;
  const int tid = threadIdx.x;

  __shared__ unsigned long long skey[SORTN];
  __shared__ unsigned int csum[256];
  __shared__ int s_cut, s_cnt;
  __shared__ float sx1[1000], sy1[1000], sx2[1000], sy2[1000], sar[1000], ssc[1000];
  __shared__ float4 sbx[1000];
  __shared__ unsigned short slab[1000];
  __shared__ int keptidx[100];
  __shared__ unsigned char skeep[1000];
  __shared__ int s_k;

  const unsigned int* h = hist + n * NBIN;

  // ---- cutoff bin: largest cut with suffix-count >= 1000 ----
  if (tid < 256) {
    unsigned int s = 0;
    for (int b = tid * 8; b < tid * 8 + 8; ++b) s += h[b];
    csum[tid] = s;
  }
  if (tid == 0) s_cnt = 0;
  __syncthreads();
  if (tid == 0) {
    long long acc = 0; int cut = 0;
    for (int cch = 255; cch >= 0; --cch) {
      if (acc + (long long)csum[cch] >= 1000) {
        for (int b = cch * 8 + 7; b >= cch * 8; --b) {
          acc += h[b];
          if (acc >= 1000) { cut = b; break; }
        }
        break;
      }
      acc += csum[cch];
    }
    s_cut = cut;
  }
  __syncthreads();
  const int cut = s_cut;

  // ---- compact survivors into sort keys ----
  int bigc = (int)bigcount[n]; if (bigc > BIGCAP) bigc = BIGCAP;
  for (int e = tid; e < bigc; e += 1024) {
    float2 v = big[(size_t)n * BIGCAP + e];
    float x = v.x;
    int b = (int)((x - STATIC_X) * 256.0f); if (b > NBIN - 1) b = NBIN - 1;
    if (b >= cut) {
      float s = 1.0f / (1.0f + expf(-x));
      if (s > 0.05f) {
        int pos = atomicAdd(&s_cnt, 1);
        if (pos < SORTN) {
          unsigned int idx = __float_as_uint(v.y);
          skey[pos] = ((unsigned long long)__float_as_uint(s) << 32) |
                      (unsigned long long)(0xFFFFFFFFu - idx);
        }
      }
    }
  }
  __syncthreads();
  int cnt = s_cnt; if (cnt > SORTN) cnt = SORTN;
  for (int p = tid; p < SORTN; p += 1024)
    if (p >= cnt) skey[p] = 0ull;
  __syncthreads();

  // ---- bitonic ascending sort of 2048 keys ----
  for (int k = 2; k <= SORTN; k <<= 1) {
    for (int j = k >> 1; j > 0; j >>= 1) {
      for (int t = tid; t < SORTN; t += 1024) {
        int ixj = t ^ j;
        if (ixj > t) {
          unsigned long long va = skey[t], vb = skey[ixj];
          bool asc = ((t & k) == 0);
          if (asc ? (va > vb) : (va < vb)) { skey[t] = vb; skey[ixj] = va; }
        }
      }
      __syncthreads();
    }
  }

  // ---- extract top-1000 and decode boxes ----
  if (tid < 1000) {
    const int i = tid;
    unsigned long long key = skey[SORTN - 1 - i];
    bool ok = (i < cnt) && (key != 0ull);
    int   idx = ok ? (int)(0xFFFFFFFFu - (unsigned int)(key & 0xFFFFFFFFu)) : 0;
    float sc  = ok ? __uint_as_float((unsigned int)(key >> 32)) : -1.0f;

    int c   = idx % C_;
    int loc = idx / C_;
    int a   = loc % A_;
    int hw  = loc / A_;
    int hh  = hw / W_;
    int ww  = hw - hh * W_;
    int rb  = ((n * A_ + a) * 4) * HW_ + hh * W_ + ww;
    float r0 = reg[rb], r1 = reg[rb + HW_], r2 = reg[rb + 2*HW_], r3 = reg[rb + 3*HW_];
    float4 an = reinterpret_cast<const float4*>(anchors)[loc];
    float wdt = an.z - an.x + 1.0f, hgt = an.w - an.y + 1.0f;
    float cx  = an.x + 0.5f * wdt, cy = an.y + 0.5f * hgt;
    float dx = r0 / 10.0f, dy = r1 / 10.0f;
    float dw = fminf(r2 / 5.0f, CLIPV), dh = fminf(r3 / 5.0f, CLIPV);
    float pcx = dx * wdt + cx, pcy = dy * hgt + cy;
    float pw = expf(dw) * wdt, ph = expf(dh) * hgt;
    float x1 = pcx - 0.5f * pw, y1 = pcy - 0.5f * ph;
    float x2 = pcx + 0.5f * pw - 1.0f, y2 = pcy + 0.5f * ph - 1.0f;
    x1 = fminf(fmaxf(x1, 0.0f), (float)(W_*8) - 1.0f);
    y1 = fminf(fmaxf(y1, 0.0f), (float)(H_*8) - 1.0f);
    x2 = fminf(fmaxf(x2, 0.0f), (float)(W_*8) - 1.0f);
    y2 = fminf(fmaxf(y2, 0.0f), (float)(H_*8) - 1.0f);
    bool valid = sc > 0.0f;
    if ((x2 - x1 + 1.0f < 0.0f) || (y2 - y1 + 1.0f < 0.0f)) valid = false;
    int   label = c + 1;
    float off = (float)label * 4096.0f;
    // offset boxes in f32 (replicates reference's rounding at large magnitude)
    float ox1 = x1 + off, oy1 = y1 + off, ox2 = x2 + off, oy2 = y2 + off;
    sx1[i] = ox1; sy1[i] = oy1; sx2[i] = ox2; sy2[i] = oy2;
    sar[i] = (ox2 - ox1 + 1.0f) * (oy2 - oy1 + 1.0f);
    sbx[i] = make_float4(x1, y1, x2, y2);
    slab[i] = (unsigned short)label;
    ssc[i] = valid ? sc : -1.0f;
  }
  __syncthreads();

  // ---- single-wave greedy NMS, kept boxes in registers, early-exit at 100 ----
  if (tid < 64) {
    const int lane = tid;
    float ka_x1 = 0, ka_y1 = 0, ka_x2 = 0, ka_y2 = 0, ka_ar = 0;
    float kb_x1 = 0, kb_y1 = 0, kb_x2 = 0, kb_y2 = 0, kb_ar = 0;
    int k = 0;
    for (int i = 0; i < 1000; ++i) {
      if (k >= 100) break;
      float sc = ssc[i];
      float x1 = sx1[i], y1 = sy1[i], x2 = sx2[i], y2 = sy2[i], ar = sar[i];
      bool sup = false;
      if (lane < k) {
        float iw = fminf(x2, ka_x2) - fmaxf(x1, ka_x1) + 1.0f;
        float ih = fminf(y2, ka_y2) - fmaxf(y1, ka_y1) + 1.0f;
        if (iw > 0.0f && ih > 0.0f) {
          float inter = iw * ih;
          sup = inter / (ar + ka_ar - inter) > 0.5f;
        }
      }
      if (lane + 64 < k) {
        float iw = fminf(x2, kb_x2) - fmaxf(x1, kb_x1) + 1.0f;
        float ih = fminf(y2, kb_y2) - fmaxf(y1, kb_y1) + 1.0f;
        if (iw > 0.0f && ih > 0.0f) {
          float inter = iw * ih;
          sup = sup || (inter / (ar + kb_ar - inter) > 0.5f);
        }
      }
      bool any = __any(sup);
      bool valid = sc > 0.0f;
      if (valid && !any) {
        if (lane == k)      { ka_x1 = x1; ka_y1 = y1; ka_x2 = x2; ka_y2 = y2; ka_ar = ar; }
        if (lane == k - 64) { kb_x1 = x1; kb_y1 = y1; kb_x2 = x2; kb_y2 = y2; kb_ar = ar; }
        if (lane == 0) { keptidx[k] = i; skeep[i] = 1; }
        ++k;
      } else if (lane == 0) {
        skeep[i] = 0;
      }
    }
    if (lane == 0) {
      if (k < 100) {   // pad with not-kept entries in ascending index order
        int fill = k;
        for (int q = 0; q < 1000 && fill < 100; ++q)
          if (!skeep[q]) keptidx[fill++] = q;
      }
      s_k = k;
    }
  }
  __syncthreads();

  // ---- emit ----
  if (tid < 100) {
    int s = tid;
    int f = keptidx[s];
    bool isk = s < s_k;
    float4 b = sbx[f];
    float sc  = isk ? ssc[f] : -1.0f;
    float lab = (sc > 0.0f) ? (float)slab[f] : 0.0f;
    int ob = (n * 100 + s) * 4;
    out[ob + 0] = b.x; out[ob + 1] = b.y; out[ob + 2] = b.z; out[ob + 3] = b.w;
    out[800  + n * 100 + s] = sc;
    out[1000 + n * 100 + s] = lab;
  }
}

extern "C" void kernel_launch(void* const* d_in, const int* in_sizes, int n_in,
                              void* d_out, int out_size, void* d_ws, size_t ws_size,
                              hipStream_t stream) {
  const float* cls = (const float*)d_in[0];
  const float* reg = (const float*)d_in[1];
  const float* anc = (const float*)d_in[2];
  float* out = (float*)d_out;
  char* ws = (char*)d_ws;
  unsigned int* hist     = (unsigned int*)(ws + OFF_HIST);
  unsigned int* bigcount = (unsigned int*)(ws + OFF_BIGCNT);
  float2* big            = (float2*)(ws + OFF_BIG);

  hipMemsetAsync(d_ws, 0, 16392, stream);
  dim3 g1(NB_SCAN, 2);
  scan_kernel<<<g1, TPB, 0, stream>>>(cls, hist, bigcount, big);
  selfin_kernel<<<2, 1024, 0, stream>>>(hist, bigcount, big, reg, anc, out);
}

// Round 3
// 159.412 us; speedup vs baseline: 2.6754x; 2.6754x over previous
//
#include <hip/hip_runtime.h>

// RetinaNet post-processor, MI355X. Round 3.
// N=2, A=9, C=80, H=100, W=152. PRE_NMS_TOP_N=1000, POST_TOP_N=100.
//
//  K1 scan:   2672 blocks/image x 256 thr; each block owns a contiguous 16KB
//             chunk (4 float4/thread, independent loads issued up-front).
//             Candidates (logit x > 2.0; ~15K/image, rank-1000 ~ 3.48) staged
//             in LDS, one global atomic + coalesced flush per block.
//             NO histogram, NO ballots, NO global atomics in the hot loop.
//  K2 selfin: per-image block (1024 thr): load candidate list (~120KB),
//             2048-bin LDS histogram -> exact suffix>=1000 bin cutoff,
//             compact survivors (~1010), bitonic sort 2048 u64 keys
//             (key = sigmoid_bits<<32 | ~idx == jax top_k stable order),
//             decode top-1000 boxes, single-wave register NMS (early-exit at
//             100 keeps), emit boxes/scores/labels.

#define W_    152
#define H_    100
#define A_    9
#define C_    80
#define HW_   (H_*W_)            // 15200
#define PER_IMG  (A_*C_*HW_)     // 10944000
#define PER_IMG4 (PER_IMG/4)     // 2736000
#define NBIN  2048
#define BIGCAP 24576
#define SORTN 2048
#define STATIC_X 2.0f
#define CLIPV 4.135166556742356f  // log(1000/16)

#define TPB      256
#define F4_PER_T 4
#define NB_SCAN  ((PER_IMG4 + TPB*F4_PER_T - 1) / (TPB*F4_PER_T))   // 2672
#define LCAP     256

// ws layout (bytes):
#define OFF_BIGCNT 0        // 2 u32
#define OFF_BIG    256      // 2 x BIGCAP x float2

__global__ __launch_bounds__(TPB) void scan_kernel(
    const float* __restrict__ cls,
    unsigned int* __restrict__ bigcount,
    float2* __restrict__ big) {
  const int n = blockIdx.y;
  const float4* __restrict__ in = reinterpret_cast<const float4*>(cls) + (size_t)n * PER_IMG4;
  __shared__ unsigned int lcnt, lbase;
  __shared__ float        lx[LCAP];
  __shared__ unsigned int lidx[LCAP];
  if (threadIdx.x == 0) lcnt = 0;
  __syncthreads();

  const int base = blockIdx.x * (TPB * F4_PER_T) + threadIdx.x;
  // issue 4 independent contiguous-coalesced loads up-front
  float4 v[F4_PER_T];
  int    t[F4_PER_T];
#pragma unroll
  for (int j = 0; j < F4_PER_T; ++j) {
    t[j] = base + j * TPB;
    v[j] = (t[j] < PER_IMG4) ? in[t[j]]
                             : make_float4(-100.f, -100.f, -100.f, -100.f);
  }
#pragma unroll
  for (int j = 0; j < F4_PER_T; ++j) {
    const float4 vv = v[j];
    if (vv.x > STATIC_X || vv.y > STATIC_X || vv.z > STATIC_X || vv.w > STATIC_X) {
      // rare path (~0.5% of threads): index math + LDS staging
      const int f0  = t[j] * 4;
      const int ac  = f0 / HW_;
      const int rem = f0 - ac * HW_;
      const int h   = rem / W_;
      const int w0  = rem - h * W_;
      const int a   = ac / C_;
      const int c   = ac - a * C_;
      const int idx0 = ((h * W_ + w0) * A_ + a) * C_ + c;   // +720 per elem
      const float xs[4] = {vv.x, vv.y, vv.z, vv.w};
#pragma unroll
      for (int e = 0; e < 4; ++e) {
        if (xs[e] > STATIC_X) {
          unsigned pos = atomicAdd(&lcnt, 1u);
          if (pos < LCAP) {
            lx[pos]   = xs[e];
            lidx[pos] = (unsigned)(idx0 + e * 720);
          }
        }
      }
    }
  }
  __syncthreads();
  if (threadIdx.x == 0) {
    unsigned c2 = lcnt; if (c2 > LCAP) c2 = LCAP;
    lbase = (c2 > 0) ? atomicAdd(&bigcount[n], c2) : 0u;
    lcnt = c2;
  }
  __syncthreads();
  const unsigned c2 = lcnt;
  for (unsigned e = threadIdx.x; e < c2; e += TPB) {
    unsigned pos = lbase + e;
    if (pos < BIGCAP)
      big[(size_t)n * BIGCAP + pos] = make_float2(lx[e], __uint_as_float(lidx[e]));
  }
}

__global__ __launch_bounds__(1024) void selfin_kernel(
    const unsigned int* __restrict__ bigcount,
    const float2* __restrict__ big,
    const float* __restrict__ reg, const float* __restrict__ anchors,
    float* __restrict__ out) {
  const int n = blockIdx.x;
  const int tid = threadIdx.x;

  __shared__ unsigned long long skey[SORTN];
  __shared__ unsigned int shist[NBIN];
  __shared__ unsigned int csum[256];
  __shared__ int s_cut, s_cnt;
  __shared__ float sx1[1000], sy1[1000], sx2[1000], sy2[1000], sar[1000], ssc[1000];
  __shared__ float4 sbx[1000];
  __shared__ unsigned short slab[1000];
  __shared__ int keptidx[100];
  __shared__ unsigned char skeep[1000];
  __shared__ int s_k;

  // ---- LDS histogram of candidates ----
  shist[tid] = 0; shist[tid + 1024] = 0;
  if (tid == 0) s_cnt = 0;
  __syncthreads();
  int bigc = (int)bigcount[n]; if (bigc > BIGCAP) bigc = BIGCAP;
  const float2* __restrict__ bn = big + (size_t)n * BIGCAP;
  for (int e = tid; e < bigc; e += 1024) {
    float x = bn[e].x;
    int b = (int)((x - STATIC_X) * 256.0f); if (b > NBIN - 1) b = NBIN - 1;
    atomicAdd(&shist[b], 1u);
  }
  __syncthreads();

  // ---- cutoff bin: largest cut with suffix-count >= 1000 ----
  if (tid < 256) {
    unsigned int s = 0;
    for (int b = tid * 8; b < tid * 8 + 8; ++b) s += shist[b];
    csum[tid] = s;
  }
  __syncthreads();
  if (tid == 0) {
    long long acc = 0; int cut = 0;
    for (int cch = 255; cch >= 0; --cch) {
      if (acc + (long long)csum[cch] >= 1000) {
        for (int b = cch * 8 + 7; b >= cch * 8; --b) {
          acc += shist[b];
          if (acc >= 1000) { cut = b; break; }
        }
        break;
      }
      acc += csum[cch];
    }
    s_cut = cut;
  }
  __syncthreads();
  const int cut = s_cut;

  // ---- compact survivors into sort keys ----
  for (int e = tid; e < bigc; e += 1024) {
    float2 v = bn[e];
    float x = v.x;
    int b = (int)((x - STATIC_X) * 256.0f); if (b > NBIN - 1) b = NBIN - 1;
    if (b >= cut) {
      float s = 1.0f / (1.0f + expf(-x));   // > 0.05 guaranteed at x>2
      int pos = atomicAdd(&s_cnt, 1);
      if (pos < SORTN) {
        unsigned int idx = __float_as_uint(v.y);
        skey[pos] = ((unsigned long long)__float_as_uint(s) << 32) |
                    (unsigned long long)(0xFFFFFFFFu - idx);
      }
    }
  }
  __syncthreads();
  int cnt = s_cnt; if (cnt > SORTN) cnt = SORTN;
  for (int p = tid; p < SORTN; p += 1024)
    if (p >= cnt) skey[p] = 0ull;
  __syncthreads();

  // ---- bitonic ascending sort of 2048 keys ----
  for (int k = 2; k <= SORTN; k <<= 1) {
    for (int j = k >> 1; j > 0; j >>= 1) {
#pragma unroll
      for (int u = 0; u < 2; ++u) {
        int tt = tid + u * 1024;
        int ixj = tt ^ j;
        if (ixj > tt) {
          unsigned long long va = skey[tt], vb = skey[ixj];
          bool asc = ((tt & k) == 0);
          if (asc ? (va > vb) : (va < vb)) { skey[tt] = vb; skey[ixj] = va; }
        }
      }
      __syncthreads();
    }
  }

  // ---- extract top-1000 and decode boxes ----
  if (tid < 1000) {
    const int i = tid;
    unsigned long long key = skey[SORTN - 1 - i];
    bool ok = (i < cnt) && (key != 0ull);
    int   idx = ok ? (int)(0xFFFFFFFFu - (unsigned int)(key & 0xFFFFFFFFu)) : 0;
    float sc  = ok ? __uint_as_float((unsigned int)(key >> 32)) : -1.0f;

    int c   = idx % C_;
    int loc = idx / C_;
    int a   = loc % A_;
    int hw  = loc / A_;
    int hh  = hw / W_;
    int ww  = hw - hh * W_;
    int rb  = ((n * A_ + a) * 4) * HW_ + hh * W_ + ww;
    float r0 = reg[rb], r1 = reg[rb + HW_], r2 = reg[rb + 2*HW_], r3 = reg[rb + 3*HW_];
    float4 an = reinterpret_cast<const float4*>(anchors)[loc];
    float wdt = an.z - an.x + 1.0f, hgt = an.w - an.y + 1.0f;
    float cx  = an.x + 0.5f * wdt, cy = an.y + 0.5f * hgt;
    float dx = r0 / 10.0f, dy = r1 / 10.0f;
    float dw = fminf(r2 / 5.0f, CLIPV), dh = fminf(r3 / 5.0f, CLIPV);
    float pcx = dx * wdt + cx, pcy = dy * hgt + cy;
    float pw = expf(dw) * wdt, ph = expf(dh) * hgt;
    float x1 = pcx - 0.5f * pw, y1 = pcy - 0.5f * ph;
    float x2 = pcx + 0.5f * pw - 1.0f, y2 = pcy + 0.5f * ph - 1.0f;
    x1 = fminf(fmaxf(x1, 0.0f), (float)(W_*8) - 1.0f);
    y1 = fminf(fmaxf(y1, 0.0f), (float)(H_*8) - 1.0f);
    x2 = fminf(fmaxf(x2, 0.0f), (float)(W_*8) - 1.0f);
    y2 = fminf(fmaxf(y2, 0.0f), (float)(H_*8) - 1.0f);
    bool valid = sc > 0.0f;
    if ((x2 - x1 + 1.0f < 0.0f) || (y2 - y1 + 1.0f < 0.0f)) valid = false;
    int   label = c + 1;
    float off = (float)label * 4096.0f;
    // offset boxes in f32 (replicates reference rounding at large magnitude)
    float ox1 = x1 + off, oy1 = y1 + off, ox2 = x2 + off, oy2 = y2 + off;
    sx1[i] = ox1; sy1[i] = oy1; sx2[i] = ox2; sy2[i] = oy2;
    sar[i] = (ox2 - ox1 + 1.0f) * (oy2 - oy1 + 1.0f);
    sbx[i] = make_float4(x1, y1, x2, y2);
    slab[i] = (unsigned short)label;
    ssc[i] = valid ? sc : -1.0f;
  }
  __syncthreads();

  // ---- single-wave greedy NMS, kept boxes in registers, early-exit at 100 ----
  if (tid < 64) {
    const int lane = tid;
    float ka_x1 = 0, ka_y1 = 0, ka_x2 = 0, ka_y2 = 0, ka_ar = 0;
    float kb_x1 = 0, kb_y1 = 0, kb_x2 = 0, kb_y2 = 0, kb_ar = 0;
    int k = 0;
    for (int i = 0; i < 1000; ++i) {
      if (k >= 100) break;
      float sc = ssc[i];
      float x1 = sx1[i], y1 = sy1[i], x2 = sx2[i], y2 = sy2[i], ar = sar[i];
      bool sup = false;
      if (lane < k) {
        float iw = fminf(x2, ka_x2) - fmaxf(x1, ka_x1) + 1.0f;
        float ih = fminf(y2, ka_y2) - fmaxf(y1, ka_y1) + 1.0f;
        if (iw > 0.0f && ih > 0.0f) {
          float inter = iw * ih;
          sup = inter / (ar + ka_ar - inter) > 0.5f;
        }
      }
      if (lane + 64 < k) {
        float iw = fminf(x2, kb_x2) - fmaxf(x1, kb_x1) + 1.0f;
        float ih = fminf(y2, kb_y2) - fmaxf(y1, kb_y1) + 1.0f;
        if (iw > 0.0f && ih > 0.0f) {
          float inter = iw * ih;
          sup = sup || (inter / (ar + kb_ar - inter) > 0.5f);
        }
      }
      bool any = __any(sup);
      bool valid = sc > 0.0f;
      if (valid && !any) {
        if (lane == k)      { ka_x1 = x1; ka_y1 = y1; ka_x2 = x2; ka_y2 = y2; ka_ar = ar; }
        if (lane == k - 64) { kb_x1 = x1; kb_y1 = y1; kb_x2 = x2; kb_y2 = y2; kb_ar = ar; }
        if (lane == 0) { keptidx[k] = i; skeep[i] = 1; }
        ++k;
      } else if (lane == 0) {
        skeep[i] = 0;
      }
    }
    if (lane == 0) {
      if (k < 100) {   // pad with not-kept entries in ascending index order
        int fill = k;
        for (int q = 0; q < 1000 && fill < 100; ++q)
          if (!skeep[q]) keptidx[fill++] = q;
      }
      s_k = k;
    }
  }
  __syncthreads();

  // ---- emit ----
  if (tid < 100) {
    int s = tid;
    int f = keptidx[s];
    bool isk = s < s_k;
    float4 b = sbx[f];
    float sc  = isk ? ssc[f] : -1.0f;
    float lab = (sc > 0.0f) ? (float)slab[f] : 0.0f;
    int ob = (n * 100 + s) * 4;
    out[ob + 0] = b.x; out[ob + 1] = b.y; out[ob + 2] = b.z; out[ob + 3] = b.w;
    out[800  + n * 100 + s] = sc;
    out[1000 + n * 100 + s] = lab;
  }
}

extern "C" void kernel_launch(void* const* d_in, const int* in_sizes, int n_in,
                              void* d_out, int out_size, void* d_ws, size_t ws_size,
                              hipStream_t stream) {
  const float* cls = (const float*)d_in[0];
  const float* reg = (const float*)d_in[1];
  const float* anc = (const float*)d_in[2];
  float* out = (float*)d_out;
  char* ws = (char*)d_ws;
  unsigned int* bigcount = (unsigned int*)(ws + OFF_BIGCNT);
  float2* big            = (float2*)(ws + OFF_BIG);

  hipMemsetAsync(d_ws, 0, 8, stream);
  dim3 g1(NB_SCAN, 2);
  scan_kernel<<<g1, TPB, 0, stream>>>(cls, bigcount, big);
  selfin_kernel<<<2, 1024, 0, stream>>>(bigcount, big, reg, anc, out);
}

// Round 4
// 153.873 us; speedup vs baseline: 2.7717x; 1.0360x over previous
//
#include <hip/hip_runtime.h>

// RetinaNet post-processor, MI355X. Round 4.
// N=2, A=9, C=80, H=100, W=152. PRE_NMS_TOP_N=1000, POST_TOP_N=100.
//
//  K1 scan:   (unchanged from R3) 2672 blocks/image x 256 thr, 4 float4/thread,
//             LDS-staged candidate compaction, 1 global atomic/block.
//  K2 selfin: per-image block (1024 thr):
//             - load all candidates (~15K) into REGISTERS (one global pass)
//             - 2048-bin LDS histogram -> two cutoffs (head>=384, full>=1000)
//             - collect head (<=512) -> ONE-WAVE register/shuffle bitonic sort
//               (zero barriers), exact jax top_k key order
//             - decode head, single-wave register NMS, early-exit at 100 keeps
//             - fallback to full 2048 LDS sort path if head insufficient
//               (never taken for this input; kept for correctness)

#define W_    152
#define H_    100
#define A_    9
#define C_    80
#define HW_   (H_*W_)            // 15200
#define PER_IMG  (A_*C_*HW_)     // 10944000
#define PER_IMG4 (PER_IMG/4)     // 2736000
#define NBIN  2048
#define BIGCAP 24576
#define SORTN 2048
#define HEADN 384
#define HCAP  512
#define MAXIT 24                 // BIGCAP/1024
#define STATIC_X 2.0f
#define CLIPV 4.135166556742356f  // log(1000/16)

#define TPB      256
#define F4_PER_T 4
#define NB_SCAN  ((PER_IMG4 + TPB*F4_PER_T - 1) / (TPB*F4_PER_T))   // 2672
#define LCAP     256

#define OFF_BIGCNT 0        // 2 u32
#define OFF_BIG    256      // 2 x BIGCAP x float2

__global__ __launch_bounds__(TPB) void scan_kernel(
    const float* __restrict__ cls,
    unsigned int* __restrict__ bigcount,
    float2* __restrict__ big) {
  const int n = blockIdx.y;
  const float4* __restrict__ in = reinterpret_cast<const float4*>(cls) + (size_t)n * PER_IMG4;
  __shared__ unsigned int lcnt, lbase;
  __shared__ float        lx[LCAP];
  __shared__ unsigned int lidx[LCAP];
  if (threadIdx.x == 0) lcnt = 0;
  __syncthreads();

  const int base = blockIdx.x * (TPB * F4_PER_T) + threadIdx.x;
  float4 v[F4_PER_T];
  int    t[F4_PER_T];
#pragma unroll
  for (int j = 0; j < F4_PER_T; ++j) {
    t[j] = base + j * TPB;
    v[j] = (t[j] < PER_IMG4) ? in[t[j]]
                             : make_float4(-100.f, -100.f, -100.f, -100.f);
  }
#pragma unroll
  for (int j = 0; j < F4_PER_T; ++j) {
    const float4 vv = v[j];
    if (vv.x > STATIC_X || vv.y > STATIC_X || vv.z > STATIC_X || vv.w > STATIC_X) {
      const int f0  = t[j] * 4;
      const int ac  = f0 / HW_;
      const int rem = f0 - ac * HW_;
      const int h   = rem / W_;
      const int w0  = rem - h * W_;
      const int a   = ac / C_;
      const int c   = ac - a * C_;
      const int idx0 = ((h * W_ + w0) * A_ + a) * C_ + c;
      const float xs[4] = {vv.x, vv.y, vv.z, vv.w};
#pragma unroll
      for (int e = 0; e < 4; ++e) {
        if (xs[e] > STATIC_X) {
          unsigned pos = atomicAdd(&lcnt, 1u);
          if (pos < LCAP) {
            lx[pos]   = xs[e];
            lidx[pos] = (unsigned)(idx0 + e * 720);
          }
        }
      }
    }
  }
  __syncthreads();
  if (threadIdx.x == 0) {
    unsigned c2 = lcnt; if (c2 > LCAP) c2 = LCAP;
    lbase = (c2 > 0) ? atomicAdd(&bigcount[n], c2) : 0u;
    lcnt = c2;
  }
  __syncthreads();
  const unsigned c2 = lcnt;
  for (unsigned e = threadIdx.x; e < c2; e += TPB) {
    unsigned pos = lbase + e;
    if (pos < BIGCAP)
      big[(size_t)n * BIGCAP + pos] = make_float2(lx[e], __uint_as_float(lidx[e]));
  }
}

__device__ __forceinline__ unsigned long long shfl_xor_u64(unsigned long long v, int m) {
  int lo = __shfl_xor((int)(unsigned)v, m);
  int hi = __shfl_xor((int)(unsigned)(v >> 32), m);
  return ((unsigned long long)(unsigned)hi << 32) | (unsigned)lo;
}

__device__ __forceinline__ void decode_store(
    int s, int idx, float sc, int n,
    const float* __restrict__ reg, const float* __restrict__ anchors,
    float* sx1, float* sy1, float* sx2, float* sy2, float* sar, float* ssc,
    float4* sbx, unsigned short* slab) {
  int c   = idx % C_;
  int loc = idx / C_;
  int a   = loc % A_;
  int hw  = loc / A_;
  int hh  = hw / W_;
  int ww  = hw - hh * W_;
  int rb  = ((n * A_ + a) * 4) * HW_ + hh * W_ + ww;
  float r0 = reg[rb], r1 = reg[rb + HW_], r2 = reg[rb + 2*HW_], r3 = reg[rb + 3*HW_];
  float4 an = reinterpret_cast<const float4*>(anchors)[loc];
  float wdt = an.z - an.x + 1.0f, hgt = an.w - an.y + 1.0f;
  float cx  = an.x + 0.5f * wdt, cy = an.y + 0.5f * hgt;
  float dx = r0 / 10.0f, dy = r1 / 10.0f;
  float dw = fminf(r2 / 5.0f, CLIPV), dh = fminf(r3 / 5.0f, CLIPV);
  float pcx = dx * wdt + cx, pcy = dy * hgt + cy;
  float pw = expf(dw) * wdt, ph = expf(dh) * hgt;
  float x1 = pcx - 0.5f * pw, y1 = pcy - 0.5f * ph;
  float x2 = pcx + 0.5f * pw - 1.0f, y2 = pcy + 0.5f * ph - 1.0f;
  x1 = fminf(fmaxf(x1, 0.0f), (float)(W_*8) - 1.0f);
  y1 = fminf(fmaxf(y1, 0.0f), (float)(H_*8) - 1.0f);
  x2 = fminf(fmaxf(x2, 0.0f), (float)(W_*8) - 1.0f);
  y2 = fminf(fmaxf(y2, 0.0f), (float)(H_*8) - 1.0f);
  bool valid = sc > 0.0f;
  if ((x2 - x1 + 1.0f < 0.0f) || (y2 - y1 + 1.0f < 0.0f)) valid = false;
  int   label = c + 1;
  float off = (float)label * 4096.0f;
  float ox1 = x1 + off, oy1 = y1 + off, ox2 = x2 + off, oy2 = y2 + off;
  sx1[s] = ox1; sy1[s] = oy1; sx2[s] = ox2; sy2[s] = oy2;
  sar[s] = (ox2 - ox1 + 1.0f) * (oy2 - oy1 + 1.0f);
  sbx[s] = make_float4(x1, y1, x2, y2);
  slab[s] = (unsigned short)label;
  ssc[s] = valid ? sc : -1.0f;
}

__global__ __launch_bounds__(1024) void selfin_kernel(
    const unsigned int* __restrict__ bigcount,
    const float2* __restrict__ big,
    const float* __restrict__ reg, const float* __restrict__ anchors,
    float* __restrict__ out) {
  const int n = blockIdx.x;
  const int tid = threadIdx.x;
  const int lane = tid & 63;

  __shared__ unsigned int shist[NBIN];
  __shared__ unsigned int csum[256];
  __shared__ unsigned long long headkey[HCAP];
  __shared__ unsigned long long ssort[HCAP];
  __shared__ unsigned long long skey[SORTN];
  __shared__ int s_cutH, s_cut1000, s_hcnt, s_cnt, s_fb, s_k;
  __shared__ float sx1[1000], sy1[1000], sx2[1000], sy2[1000], sar[1000], ssc[1000];
  __shared__ float4 sbx[1000];
  __shared__ unsigned short slab[1000];
  __shared__ int keptidx[100];
  __shared__ unsigned char skeep[1000];

  // ---- init ----
  shist[tid] = 0; shist[tid + 1024] = 0;
  if (tid < HCAP) headkey[tid] = 0ull;
  if (tid == 0) { s_hcnt = 0; s_cnt = 0; s_fb = 0; }
  __syncthreads();

  // ---- single global pass: candidates -> registers ----
  int bigc = (int)bigcount[n]; if (bigc > BIGCAP) bigc = BIGCAP;
  const float2* __restrict__ bn = big + (size_t)n * BIGCAP;
  float rx[MAXIT]; unsigned ridx[MAXIT];
#pragma unroll
  for (int it = 0; it < MAXIT; ++it) {
    int e = tid + (it << 10);
    float2 v = (e < bigc) ? bn[e] : make_float2(-1.0e9f, 0.0f);
    rx[it] = v.x; ridx[it] = __float_as_uint(v.y);
  }

  // ---- LDS histogram ----
#pragma unroll
  for (int it = 0; it < MAXIT; ++it) {
    float x = rx[it];
    if (x > STATIC_X) {
      int b = (int)((x - STATIC_X) * 256.0f); if (b > NBIN - 1) b = NBIN - 1;
      atomicAdd(&shist[b], 1u);
    }
  }
  __syncthreads();

  // ---- cutoffs: head (>=HEADN) and full (>=1000) ----
  if (tid < 256) {
    unsigned int s = 0;
    for (int b = tid * 8; b < tid * 8 + 8; ++b) s += shist[b];
    csum[tid] = s;
  }
  __syncthreads();
  if (tid == 0) {
    int acc = 0, cutH = -1, cutF = -1;
    for (int cch = 255; cch >= 0; --cch) {
      int nacc = acc + (int)csum[cch];
      if (cutH < 0 && nacc >= HEADN) {
        int a = acc;
        for (int b = cch * 8 + 7; b >= cch * 8; --b) { a += (int)shist[b]; if (a >= HEADN) { cutH = b; break; } }
      }
      if (cutF < 0 && nacc >= 1000) {
        int a = acc;
        for (int b = cch * 8 + 7; b >= cch * 8; --b) { a += (int)shist[b]; if (a >= 1000) { cutF = b; break; } }
      }
      acc = nacc;
      if (cutH >= 0 && cutF >= 0) break;
    }
    s_cutH = (cutH < 0) ? 0 : cutH;
    s_cut1000 = (cutF < 0) ? 0 : cutF;
  }
  __syncthreads();
  const int cutH = s_cutH;

  // ---- collect head keys (<= ~400, cap 512) ----
#pragma unroll
  for (int it = 0; it < MAXIT; ++it) {
    float x = rx[it];
    if (x > STATIC_X) {
      int b = (int)((x - STATIC_X) * 256.0f); if (b > NBIN - 1) b = NBIN - 1;
      if (b >= cutH) {
        float s = 1.0f / (1.0f + expf(-x));
        int pos = atomicAdd(&s_hcnt, 1);
        if (pos < HCAP)
          headkey[pos] = ((unsigned long long)__float_as_uint(s) << 32) |
                         (unsigned long long)(0xFFFFFFFFu - ridx[it]);
        else if (pos == HCAP)
          s_fb = 1;   // head overflow -> fallback
      }
    }
  }
  __syncthreads();
  const int hcnt = (s_hcnt < HCAP) ? s_hcnt : HCAP;

  // ---- one-wave register/shuffle bitonic sort of 512 keys, zero barriers ----
  if (tid < 64) {
    unsigned long long k8[8];
#pragma unroll
    for (int r = 0; r < 8; ++r) k8[r] = headkey[r * 64 + lane];
#pragma unroll
    for (int k = 2; k <= 512; k <<= 1) {
#pragma unroll
      for (int j = k >> 1; j > 0; j >>= 1) {
        if (j >= 64) {
          const int jr = j >> 6;
#pragma unroll
          for (int r = 0; r < 8; ++r) {
            if ((r & jr) == 0) {
              const int r2 = r | jr;
              const bool asc = ((r & (k >> 6)) == 0);
              unsigned long long a = k8[r], b = k8[r2];
              if (asc ? (a > b) : (a < b)) { k8[r] = b; k8[r2] = a; }
            }
          }
        } else {
#pragma unroll
          for (int r = 0; r < 8; ++r) {
            unsigned long long o = shfl_xor_u64(k8[r], j);
            const bool is_lower = ((lane & j) == 0);
            const bool asc = (k >= 64) ? ((r & (k >> 6)) == 0) : ((lane & k) == 0);
            unsigned long long mn = (k8[r] < o) ? k8[r] : o;
            unsigned long long mx = (k8[r] < o) ? o : k8[r];
            k8[r] = (is_lower == asc) ? mn : mx;
          }
        }
      }
    }
    // write back descending: rank s = ascending[511-s]
#pragma unroll
    for (int r = 0; r < 8; ++r) ssort[511 - (r * 64 + lane)] = k8[r];
  }
  __syncthreads();

  // ---- decode head items ----
  if (tid < hcnt) {
    unsigned long long key = ssort[tid];
    int idx = (int)(0xFFFFFFFFu - (unsigned)(key & 0xFFFFFFFFu));
    float sc = __uint_as_float((unsigned)(key >> 32));
    decode_store(tid, idx, sc, n, reg, anchors, sx1, sy1, sx2, sy2, sar, ssc, sbx, slab);
  }
  __syncthreads();

  // ---- single-wave NMS over sorted head (all items valid), early-exit at 100 ----
  if (tid < 64) {
    float ka_x1 = 0, ka_y1 = 0, ka_x2 = 0, ka_y2 = 0, ka_ar = 0;
    float kb_x1 = 0, kb_y1 = 0, kb_x2 = 0, kb_y2 = 0, kb_ar = 0;
    int k = 0;
    for (int i = 0; i < hcnt; ++i) {
      if (k >= 100) break;
      float x1 = sx1[i], y1 = sy1[i], x2 = sx2[i], y2 = sy2[i], ar = sar[i];
      bool sup = false;
      if (lane < k) {
        float iw = fminf(x2, ka_x2) - fmaxf(x1, ka_x1) + 1.0f;
        float ih = fminf(y2, ka_y2) - fmaxf(y1, ka_y1) + 1.0f;
        if (iw > 0.0f && ih > 0.0f) {
          float inter = iw * ih;
          sup = inter / (ar + ka_ar - inter) > 0.5f;
        }
      }
      if (lane + 64 < k) {
        float iw = fminf(x2, kb_x2) - fmaxf(x1, kb_x1) + 1.0f;
        float ih = fminf(y2, kb_y2) - fmaxf(y1, kb_y1) + 1.0f;
        if (iw > 0.0f && ih > 0.0f) {
          float inter = iw * ih;
          sup = sup || (inter / (ar + kb_ar - inter) > 0.5f);
        }
      }
      if (!__any(sup)) {
        if (lane == k)      { ka_x1 = x1; ka_y1 = y1; ka_x2 = x2; ka_y2 = y2; ka_ar = ar; }
        if (lane == k - 64) { kb_x1 = x1; kb_y1 = y1; kb_x2 = x2; kb_y2 = y2; kb_ar = ar; }
        if (lane == 0) keptidx[k] = i;
        ++k;
      }
    }
    if (lane == 0) {
      s_k = k;
      if (k < 100) s_fb = 1;     // not enough keeps in head -> fallback
    }
  }
  __syncthreads();

  if (s_fb == 0) {
    // ---- fast emit: all 100 outputs are keeps ----
    if (tid < 100) {
      int f = keptidx[tid];
      float4 b = sbx[f];
      int ob = (n * 100 + tid) * 4;
      out[ob + 0] = b.x; out[ob + 1] = b.y; out[ob + 2] = b.z; out[ob + 3] = b.w;
      out[800  + n * 100 + tid] = ssc[f];
      out[1000 + n * 100 + tid] = (float)slab[f];
    }
    return;
  }

  // ================= fallback: full R3 path (never taken for bench input) ===
  const int cut = s_cut1000;
#pragma unroll
  for (int it = 0; it < MAXIT; ++it) {
    float x = rx[it];
    if (x > STATIC_X) {
      int b = (int)((x - STATIC_X) * 256.0f); if (b > NBIN - 1) b = NBIN - 1;
      if (b >= cut) {
        float s = 1.0f / (1.0f + expf(-x));
        int pos = atomicAdd(&s_cnt, 1);
        if (pos < SORTN)
          skey[pos] = ((unsigned long long)__float_as_uint(s) << 32) |
                      (unsigned long long)(0xFFFFFFFFu - ridx[it]);
      }
    }
  }
  __syncthreads();
  int cnt = s_cnt; if (cnt > SORTN) cnt = SORTN;
  for (int p = tid; p < SORTN; p += 1024)
    if (p >= cnt) skey[p] = 0ull;
  __syncthreads();
  for (int k = 2; k <= SORTN; k <<= 1) {
    for (int j = k >> 1; j > 0; j >>= 1) {
#pragma unroll
      for (int u = 0; u < 2; ++u) {
        int tt = tid + u * 1024;
        int ixj = tt ^ j;
        if (ixj > tt) {
          unsigned long long va = skey[tt], vb = skey[ixj];
          bool asc = ((tt & k) == 0);
          if (asc ? (va > vb) : (va < vb)) { skey[tt] = vb; skey[ixj] = va; }
        }
      }
      __syncthreads();
    }
  }
  if (tid < 1000) {
    unsigned long long key = skey[SORTN - 1 - tid];
    bool ok = (tid < cnt) && (key != 0ull);
    int   idx = ok ? (int)(0xFFFFFFFFu - (unsigned)(key & 0xFFFFFFFFu)) : 0;
    float sc  = ok ? __uint_as_float((unsigned)(key >> 32)) : -1.0f;
    decode_store(tid, idx, sc, n, reg, anchors, sx1, sy1, sx2, sy2, sar, ssc, sbx, slab);
  }
  __syncthreads();
  if (tid < 64) {
    float ka_x1 = 0, ka_y1 = 0, ka_x2 = 0, ka_y2 = 0, ka_ar = 0;
    float kb_x1 = 0, kb_y1 = 0, kb_x2 = 0, kb_y2 = 0, kb_ar = 0;
    int k = 0;
    for (int i = 0; i < 1000; ++i) {
      if (k >= 100) break;
      float sc = ssc[i];
      float x1 = sx1[i], y1 = sy1[i], x2 = sx2[i], y2 = sy2[i], ar = sar[i];
      bool sup = false;
      if (lane < k) {
        float iw = fminf(x2, ka_x2) - fmaxf(x1, ka_x1) + 1.0f;
        float ih = fminf(y2, ka_y2) - fmaxf(y1, ka_y1) + 1.0f;
        if (iw > 0.0f && ih > 0.0f) {
          float inter = iw * ih;
          sup = inter / (ar + ka_ar - inter) > 0.5f;
        }
      }
      if (lane + 64 < k) {
        float iw = fminf(x2, kb_x2) - fmaxf(x1, kb_x1) + 1.0f;
        float ih = fminf(y2, kb_y2) - fmaxf(y1, kb_y1) + 1.0f;
        if (iw > 0.0f && ih > 0.0f) {
          float inter = iw * ih;
          sup = sup || (inter / (ar + kb_ar - inter) > 0.5f);
        }
      }
      bool any = __any(sup);
      bool valid = sc > 0.0f;
      if (valid && !any) {
        if (lane == k)      { ka_x1 = x1; ka_y1 = y1; ka_x2 = x2; ka_y2 = y2; ka_ar = ar; }
        if (lane == k - 64) { kb_x1 = x1; kb_y1 = y1; kb_x2 = x2; kb_y2 = y2; kb_ar = ar; }
        if (lane == 0) { keptidx[k] = i; skeep[i] = 1; }
        ++k;
      } else if (lane == 0) {
        skeep[i] = 0;
      }
    }
    if (lane == 0) {
      if (k < 100) {
        int fill = k;
        for (int q = 0; q < 1000 && fill < 100; ++q)
          if (!skeep[q]) keptidx[fill++] = q;
      }
      s_k = k;
    }
  }
  __syncthreads();
  if (tid < 100) {
    int f = keptidx[tid];
    bool isk = tid < s_k;
    float4 b = sbx[f];
    float sc  = isk ? ssc[f] : -1.0f;
    float lab = (sc > 0.0f) ? (float)slab[f] : 0.0f;
    int ob = (n * 100 + tid) * 4;
    out[ob + 0] = b.x; out[ob + 1] = b.y; out[ob + 2] = b.z; out[ob + 3] = b.w;
    out[800  + n * 100 + tid] = sc;
    out[1000 + n * 100 + tid] = lab;
  }
}

extern "C" void kernel_launch(void* const* d_in, const int* in_sizes, int n_in,
                              void* d_out, int out_size, void* d_ws, size_t ws_size,
                              hipStream_t stream) {
  const float* cls = (const float*)d_in[0];
  const float* reg = (const float*)d_in[1];
  const float* anc = (const float*)d_in[2];
  float* out = (float*)d_out;
  char* ws = (char*)d_ws;
  unsigned int* bigcount = (unsigned int*)(ws + OFF_BIGCNT);
  float2* big            = (float2*)(ws + OFF_BIG);

  hipMemsetAsync(d_ws, 0, 8, stream);
  dim3 g1(NB_SCAN, 2);
  scan_kernel<<<g1, TPB, 0, stream>>>(cls, bigcount, big);
  selfin_kernel<<<2, 1024, 0, stream>>>(bigcount, big, reg, anc, out);
}

// Round 5
// 132.754 us; speedup vs baseline: 3.2126x; 1.1591x over previous
//
#include <hip/hip_runtime.h>

// RetinaNet post-processor, MI355X. Round 5.
// N=2, A=9, C=80, H=100, W=152. PRE_NMS_TOP_N=1000, POST_TOP_N=100.
//
//  K1 scan:   1336 blocks/image x 256 thr, 8 float4/thread (32KB/block).
//             Emits TWO candidate lists via LDS staging:
//               A: logits > 3.65  (~715/image; fast path)
//               B: logits > 2.0   (~15K/image; fallback only)
//  K2 selfin: per-image block (1024 thr) fast path:
//               - load list A (1 key/thread) into LDS
//               - rank-selection sort (1024 broadcast compares/thread, no
//                 barriers, no shuffles) -> exact jax top_k order
//               - decode top-256, single-wave register NMS (validity-checked,
//                 early-exit at 100 keeps), emit
//             fallback (count out of [256,1024] or keeps<100): full R3 path
//             over list B (hist cutoff + 2048 bitonic + NMS + padding).
//             Never taken for the bench input; preserved for correctness.

#define W_    152
#define H_    100
#define A_    9
#define C_    80
#define HW_   (H_*W_)            // 15200
#define PER_IMG  (A_*C_*HW_)     // 10944000
#define PER_IMG4 (PER_IMG/4)     // 2736000
#define NBIN  2048
#define BIGB_CAP 24576
#define BIGA_CAP 4096
#define SORTN 2048
#define FASTN 1024
#define NDEC  256
#define THRB 2.0f
#define THRA 3.65f
#define CLIPV 4.135166556742356f  // log(1000/16)

#define TPB      256
#define F4_PER_T 8
#define CHUNK    (TPB*F4_PER_T)                       // 2048 float4
#define NB_SCAN  ((PER_IMG4 + CHUNK - 1) / CHUNK)     // 1336
#define LCAPB 256
#define LCAPA 64

// ws layout (bytes):
#define OFF_CNTA 0        // 2 u32
#define OFF_CNTB 8        // 2 u32
#define OFF_BIGA 256                          // 2 x 4096 x 8B = 64KB
#define OFF_BIGB (256 + 2*BIGA_CAP*8)         // 2 x 24576 x 8B

__global__ __launch_bounds__(TPB) void scan_kernel(
    const float* __restrict__ cls,
    unsigned int* __restrict__ cntA,
    unsigned int* __restrict__ cntB,
    float2* __restrict__ bigA,
    float2* __restrict__ bigB) {
  const int n = blockIdx.y;
  const float4* __restrict__ in = reinterpret_cast<const float4*>(cls) + (size_t)n * PER_IMG4;
  __shared__ unsigned int lcntA, lcntB, lbaseA, lbaseB;
  __shared__ float        lxA[LCAPA]; __shared__ unsigned int liA[LCAPA];
  __shared__ float        lxB[LCAPB]; __shared__ unsigned int liB[LCAPB];
  if (threadIdx.x == 0) { lcntA = 0; lcntB = 0; }
  __syncthreads();

  const int base = blockIdx.x * CHUNK + threadIdx.x;
  float4 v[F4_PER_T];
  int    t[F4_PER_T];
#pragma unroll
  for (int j = 0; j < F4_PER_T; ++j) {
    t[j] = base + j * TPB;
    v[j] = (t[j] < PER_IMG4) ? in[t[j]]
                             : make_float4(-100.f, -100.f, -100.f, -100.f);
  }
#pragma unroll
  for (int j = 0; j < F4_PER_T; ++j) {
    const float4 vv = v[j];
    if (vv.x > THRB || vv.y > THRB || vv.z > THRB || vv.w > THRB) {
      // rare path (~1.5% of quads): index math + LDS staging
      const int f0  = t[j] * 4;
      const int ac  = f0 / HW_;
      const int rem = f0 - ac * HW_;
      const int h   = rem / W_;
      const int w0  = rem - h * W_;
      const int a   = ac / C_;
      const int c   = ac - a * C_;
      const int idx0 = ((h * W_ + w0) * A_ + a) * C_ + c;   // +720 per elem
      const float xs[4] = {vv.x, vv.y, vv.z, vv.w};
#pragma unroll
      for (int e = 0; e < 4; ++e) {
        const float x = xs[e];
        if (x > THRB) {
          unsigned pos = atomicAdd(&lcntB, 1u);
          if (pos < LCAPB) { lxB[pos] = x; liB[pos] = (unsigned)(idx0 + e * 720); }
          if (x > THRA) {
            unsigned pa = atomicAdd(&lcntA, 1u);
            if (pa < LCAPA) { lxA[pa] = x; liA[pa] = (unsigned)(idx0 + e * 720); }
          }
        }
      }
    }
  }
  __syncthreads();
  if (threadIdx.x == 0) {
    unsigned cA = lcntA; if (cA > LCAPA) cA = LCAPA;
    unsigned cB = lcntB; if (cB > LCAPB) cB = LCAPB;
    lbaseA = cA ? atomicAdd(&cntA[n], cA) : 0u;
    lbaseB = cB ? atomicAdd(&cntB[n], cB) : 0u;
    lcntA = cA; lcntB = cB;
  }
  __syncthreads();
  const unsigned cA = lcntA, cB = lcntB;
  if (threadIdx.x < cA) {
    unsigned pos = lbaseA + threadIdx.x;
    if (pos < BIGA_CAP)
      bigA[(size_t)n * BIGA_CAP + pos] = make_float2(lxA[threadIdx.x], __uint_as_float(liA[threadIdx.x]));
  }
  for (unsigned e = threadIdx.x; e < cB; e += TPB) {
    unsigned pos = lbaseB + e;
    if (pos < BIGB_CAP)
      bigB[(size_t)n * BIGB_CAP + pos] = make_float2(lxB[e], __uint_as_float(liB[e]));
  }
}

__device__ __forceinline__ void decode_store(
    int s, int idx, float sc, int n,
    const float* __restrict__ reg, const float* __restrict__ anchors,
    float* sx1, float* sy1, float* sx2, float* sy2, float* sar, float* ssc,
    float4* sbx, unsigned short* slab) {
  int c   = idx % C_;
  int loc = idx / C_;
  int a   = loc % A_;
  int hw  = loc / A_;
  int hh  = hw / W_;
  int ww  = hw - hh * W_;
  int rb  = ((n * A_ + a) * 4) * HW_ + hh * W_ + ww;
  float r0 = reg[rb], r1 = reg[rb + HW_], r2 = reg[rb + 2*HW_], r3 = reg[rb + 3*HW_];
  float4 an = reinterpret_cast<const float4*>(anchors)[loc];
  float wdt = an.z - an.x + 1.0f, hgt = an.w - an.y + 1.0f;
  float cx  = an.x + 0.5f * wdt, cy = an.y + 0.5f * hgt;
  float dx = r0 / 10.0f, dy = r1 / 10.0f;
  float dw = fminf(r2 / 5.0f, CLIPV), dh = fminf(r3 / 5.0f, CLIPV);
  float pcx = dx * wdt + cx, pcy = dy * hgt + cy;
  float pw = expf(dw) * wdt, ph = expf(dh) * hgt;
  float x1 = pcx - 0.5f * pw, y1 = pcy - 0.5f * ph;
  float x2 = pcx + 0.5f * pw - 1.0f, y2 = pcy + 0.5f * ph - 1.0f;
  x1 = fminf(fmaxf(x1, 0.0f), (float)(W_*8) - 1.0f);
  y1 = fminf(fmaxf(y1, 0.0f), (float)(H_*8) - 1.0f);
  x2 = fminf(fmaxf(x2, 0.0f), (float)(W_*8) - 1.0f);
  y2 = fminf(fmaxf(y2, 0.0f), (float)(H_*8) - 1.0f);
  bool valid = sc > 0.0f;
  if ((x2 - x1 + 1.0f < 0.0f) || (y2 - y1 + 1.0f < 0.0f)) valid = false;
  int   label = c + 1;
  float off = (float)label * 4096.0f;
  // offset boxes in f32 (replicates reference rounding at large magnitude)
  float ox1 = x1 + off, oy1 = y1 + off, ox2 = x2 + off, oy2 = y2 + off;
  sx1[s] = ox1; sy1[s] = oy1; sx2[s] = ox2; sy2[s] = oy2;
  sar[s] = (ox2 - ox1 + 1.0f) * (oy2 - oy1 + 1.0f);
  sbx[s] = make_float4(x1, y1, x2, y2);
  slab[s] = (unsigned short)label;
  ssc[s] = valid ? sc : -1.0f;
}

__global__ __launch_bounds__(1024) void selfin_kernel(
    const unsigned int* __restrict__ cntA,
    const unsigned int* __restrict__ cntB,
    const float2* __restrict__ bigA,
    const float2* __restrict__ bigB,
    const float* __restrict__ reg, const float* __restrict__ anchors,
    float* __restrict__ out) {
  const int n = blockIdx.x;
  const int tid = threadIdx.x;
  const int lane = tid & 63;

  __shared__ unsigned long long skl[FASTN];
  __shared__ unsigned long long ssort[FASTN];
  __shared__ unsigned long long skey[SORTN];     // fallback
  __shared__ unsigned int shist[NBIN];           // fallback
  __shared__ unsigned int csum[256];             // fallback
  __shared__ int s_fb, s_k, s_cut, s_cnt;
  __shared__ float sx1[1000], sy1[1000], sx2[1000], sy2[1000], sar[1000], ssc[1000];
  __shared__ float4 sbx[1000];
  __shared__ unsigned short slab[1000];
  __shared__ int keptidx[100];
  __shared__ unsigned char skeep[1000];          // fallback

  if (tid == 0) { s_fb = 0; s_cnt = 0; }

  // ---- fast collect: one key per thread from list A ----
  const int caRaw = (int)cntA[n];
  const int ca = (caRaw < FASTN) ? caRaw : FASTN;
  unsigned long long mykey = 0ull;
  if (tid < ca) {
    float2 v = bigA[(size_t)n * BIGA_CAP + tid];
    float s = 1.0f / (1.0f + expf(-v.x));   // x > 3.65 -> s > 0.97 > 0.05
    mykey = ((unsigned long long)__float_as_uint(s) << 32) |
            (unsigned long long)(0xFFFFFFFFu - __float_as_uint(v.y));
  }
  skl[tid] = mykey;
  __syncthreads();
  if (tid == 0 && (caRaw > FASTN || caRaw < NDEC)) s_fb = 1;

  // ---- rank-selection sort (descending); broadcast reads, no barriers ----
  {
    int rank = 0;
    const unsigned long long ki = mykey;
#pragma unroll 8
    for (int j = 0; j < FASTN; ++j) {
      unsigned long long kj = skl[j];
      rank += (int)((kj > ki) | ((kj == ki) & (j < tid)));
    }
    ssort[rank] = ki;
  }
  __syncthreads();

  // ---- decode top NDEC ----
  const int ndec = (ca < NDEC) ? ca : NDEC;
  if (tid < ndec) {
    unsigned long long key = ssort[tid];
    int idx = (int)(0xFFFFFFFFu - (unsigned)(key & 0xFFFFFFFFu));
    float sc = __uint_as_float((unsigned)(key >> 32));
    decode_store(tid, idx, sc, n, reg, anchors, sx1, sy1, sx2, sy2, sar, ssc, sbx, slab);
  }
  __syncthreads();

  // ---- single-wave NMS over top ndec (validity-checked), early-exit at 100 ----
  if (tid < 64) {
    float ka_x1 = 0, ka_y1 = 0, ka_x2 = 0, ka_y2 = 0, ka_ar = 0;
    float kb_x1 = 0, kb_y1 = 0, kb_x2 = 0, kb_y2 = 0, kb_ar = 0;
    int k = 0;
    for (int i = 0; i < ndec; ++i) {
      if (k >= 100) break;
      float sc = ssc[i];
      float x1 = sx1[i], y1 = sy1[i], x2 = sx2[i], y2 = sy2[i], ar = sar[i];
      bool sup = false;
      if (lane < k) {
        float iw = fminf(x2, ka_x2) - fmaxf(x1, ka_x1) + 1.0f;
        float ih = fminf(y2, ka_y2) - fmaxf(y1, ka_y1) + 1.0f;
        if (iw > 0.0f && ih > 0.0f) {
          float inter = iw * ih;
          sup = inter / (ar + ka_ar - inter) > 0.5f;
        }
      }
      if (lane + 64 < k) {
        float iw = fminf(x2, kb_x2) - fmaxf(x1, kb_x1) + 1.0f;
        float ih = fminf(y2, kb_y2) - fmaxf(y1, kb_y1) + 1.0f;
        if (iw > 0.0f && ih > 0.0f) {
          float inter = iw * ih;
          sup = sup || (inter / (ar + kb_ar - inter) > 0.5f);
        }
      }
      bool any = __any(sup);
      if ((sc > 0.0f) && !any) {
        if (lane == k)      { ka_x1 = x1; ka_y1 = y1; ka_x2 = x2; ka_y2 = y2; ka_ar = ar; }
        if (lane == k - 64) { kb_x1 = x1; kb_y1 = y1; kb_x2 = x2; kb_y2 = y2; kb_ar = ar; }
        if (lane == 0) keptidx[k] = i;
        ++k;
      }
    }
    if (lane == 0) {
      s_k = k;
      if (k < 100) s_fb = 1;   // not enough keeps in decoded head -> fallback
    }
  }
  __syncthreads();

  if (s_fb == 0) {
    if (tid < 100) {
      int f = keptidx[tid];
      float4 b = sbx[f];
      int ob = (n * 100 + tid) * 4;
      out[ob + 0] = b.x; out[ob + 1] = b.y; out[ob + 2] = b.z; out[ob + 3] = b.w;
      out[800  + n * 100 + tid] = ssc[f];
      out[1000 + n * 100 + tid] = (float)slab[f];
    }
    return;
  }

  // ================= fallback: full path over list B (never taken) =========
  shist[tid] = 0; shist[tid + 1024] = 0;
  __syncthreads();
  int bigc = (int)cntB[n]; if (bigc > BIGB_CAP) bigc = BIGB_CAP;
  const float2* __restrict__ bn = bigB + (size_t)n * BIGB_CAP;
  for (int e = tid; e < bigc; e += 1024) {
    float x = bn[e].x;
    int b = (int)((x - THRB) * 256.0f); if (b > NBIN - 1) b = NBIN - 1;
    atomicAdd(&shist[b], 1u);
  }
  __syncthreads();
  if (tid < 256) {
    unsigned int s = 0;
    for (int b = tid * 8; b < tid * 8 + 8; ++b) s += shist[b];
    csum[tid] = s;
  }
  __syncthreads();
  if (tid == 0) {
    int acc = 0, cut = 0;
    for (int cch = 255; cch >= 0; --cch) {
      int nacc = acc + (int)csum[cch];
      if (nacc >= 1000) {
        int a = acc;
        for (int b = cch * 8 + 7; b >= cch * 8; --b) { a += (int)shist[b]; if (a >= 1000) { cut = b; break; } }
        break;
      }
      acc = nacc;
    }
    s_cut = cut;
  }
  __syncthreads();
  const int cut = s_cut;
  for (int e = tid; e < bigc; e += 1024) {
    float2 v = bn[e];
    float x = v.x;
    int b = (int)((x - THRB) * 256.0f); if (b > NBIN - 1) b = NBIN - 1;
    if (b >= cut) {
      float s = 1.0f / (1.0f + expf(-x));
      int pos = atomicAdd(&s_cnt, 1);
      if (pos < SORTN)
        skey[pos] = ((unsigned long long)__float_as_uint(s) << 32) |
                    (unsigned long long)(0xFFFFFFFFu - __float_as_uint(v.y));
    }
  }
  __syncthreads();
  int cnt = s_cnt; if (cnt > SORTN) cnt = SORTN;
  for (int p = tid; p < SORTN; p += 1024)
    if (p >= cnt) skey[p] = 0ull;
  __syncthreads();
  for (int k = 2; k <= SORTN; k <<= 1) {
    for (int j = k >> 1; j > 0; j >>= 1) {
#pragma unroll
      for (int u = 0; u < 2; ++u) {
        int tt = tid + u * 1024;
        int ixj = tt ^ j;
        if (ixj > tt) {
          unsigned long long va = skey[tt], vb = skey[ixj];
          bool asc = ((tt & k) == 0);
          if (asc ? (va > vb) : (va < vb)) { skey[tt] = vb; skey[ixj] = va; }
        }
      }
      __syncthreads();
    }
  }
  if (tid < 1000) {
    unsigned long long key = skey[SORTN - 1 - tid];
    bool ok = (tid < cnt) && (key != 0ull);
    int   idx = ok ? (int)(0xFFFFFFFFu - (unsigned)(key & 0xFFFFFFFFu)) : 0;
    float sc  = ok ? __uint_as_float((unsigned)(key >> 32)) : -1.0f;
    decode_store(tid, idx, sc, n, reg, anchors, sx1, sy1, sx2, sy2, sar, ssc, sbx, slab);
  }
  __syncthreads();
  if (tid < 64) {
    float ka_x1 = 0, ka_y1 = 0, ka_x2 = 0, ka_y2 = 0, ka_ar = 0;
    float kb_x1 = 0, kb_y1 = 0, kb_x2 = 0, kb_y2 = 0, kb_ar = 0;
    int k = 0;
    for (int i = 0; i < 1000; ++i) {
      if (k >= 100) break;
      float sc = ssc[i];
      float x1 = sx1[i], y1 = sy1[i], x2 = sx2[i], y2 = sy2[i], ar = sar[i];
      bool sup = false;
      if (lane < k) {
        float iw = fminf(x2, ka_x2) - fmaxf(x1, ka_x1) + 1.0f;
        float ih = fminf(y2, ka_y2) - fmaxf(y1, ka_y1) + 1.0f;
        if (iw > 0.0f && ih > 0.0f) {
          float inter = iw * ih;
          sup = inter / (ar + ka_ar - inter) > 0.5f;
        }
      }
      if (lane + 64 < k) {
        float iw = fminf(x2, kb_x2) - fmaxf(x1, kb_x1) + 1.0f;
        float ih = fminf(y2, kb_y2) - fmaxf(y1, kb_y1) + 1.0f;
        if (iw > 0.0f && ih > 0.0f) {
          float inter = iw * ih;
          sup = sup || (inter / (ar + kb_ar - inter) > 0.5f);
        }
      }
      bool any = __any(sup);
      bool valid = sc > 0.0f;
      if (valid && !any) {
        if (lane == k)      { ka_x1 = x1; ka_y1 = y1; ka_x2 = x2; ka_y2 = y2; ka_ar = ar; }
        if (lane == k - 64) { kb_x1 = x1; kb_y1 = y1; kb_x2 = x2; kb_y2 = y2; kb_ar = ar; }
        if (lane == 0) { keptidx[k] = i; skeep[i] = 1; }
        ++k;
      } else if (lane == 0) {
        skeep[i] = 0;
      }
    }
    if (lane == 0) {
      if (k < 100) {
        int fill = k;
        for (int q = 0; q < 1000 && fill < 100; ++q)
          if (!skeep[q]) keptidx[fill++] = q;
      }
      s_k = k;
    }
  }
  __syncthreads();
  if (tid < 100) {
    int f = keptidx[tid];
    bool isk = tid < s_k;
    float4 b = sbx[f];
    float sc  = isk ? ssc[f] : -1.0f;
    float lab = (sc > 0.0f) ? (float)slab[f] : 0.0f;
    int ob = (n * 100 + tid) * 4;
    out[ob + 0] = b.x; out[ob + 1] = b.y; out[ob + 2] = b.z; out[ob + 3] = b.w;
    out[800  + n * 100 + tid] = sc;
    out[1000 + n * 100 + tid] = lab;
  }
}

extern "C" void kernel_launch(void* const* d_in, const int* in_sizes, int n_in,
                              void* d_out, int out_size, void* d_ws, size_t ws_size,
                              hipStream_t stream) {
  const float* cls = (const float*)d_in[0];
  const float* reg = (const float*)d_in[1];
  const float* anc = (const float*)d_in[2];
  float* out = (float*)d_out;
  char* ws = (char*)d_ws;
  unsigned int* cntA = (unsigned int*)(ws + OFF_CNTA);
  unsigned int* cntB = (unsigned int*)(ws + OFF_CNTB);
  float2* bigA       = (float2*)(ws + OFF_BIGA);
  float2* bigB       = (float2*)(ws + OFF_BIGB);

  hipMemsetAsync(d_ws, 0, 16, stream);
  dim3 g1(NB_SCAN, 2);
  scan_kernel<<<g1, TPB, 0, stream>>>(cls, cntA, cntB, bigA, bigB);
  selfin_kernel<<<2, 1024, 0, stream>>>(cntA, cntB, bigA, bigB, reg, anc, out);
}

// Round 6
// 98.330 us; speedup vs baseline: 4.3373x; 1.3501x over previous
//
#include <hip/hip_runtime.h>

// RetinaNet post-processor, MI355X. Round 6.
// N=2, A=9, C=80, H=100, W=152. PRE_NMS_TOP_N=1000, POST_TOP_N=100.
//
//  K1 scan:   1336 blocks/image x 256 thr, 8 float4/thread.
//             List A: logits > 3.65 (~715/image) stored as final u64 sort key
//                     (sigmoid_bits<<32 | ~idx)  == jax top_k stable order.
//             List B: logits > 2.0  (~15K/image) raw {x, idx} (fallback only).
//  K2 rank:   32 blocks/image x 256 thr. Block caches all 1024 key slots in
//             LDS; ranks 32 keys (8 thr/key x 128 compares, conflict-free),
//             scatters sorted[rank]=key to ws. Spreads the O(n^2) rank work
//             over 64 CUs (R5 did it on 1 CU's LDS pipe -> 80us).
//  K3 finish: per-image block: decode sorted[0..255], single-wave register
//             NMS (early-exit at 100 keeps), emit. Fallback to full B-list
//             path (hist cutoff + 2048 bitonic) if count out of [256,1024]
//             or keeps < 100 -- never taken for the bench input.

#define W_    152
#define H_    100
#define A_    9
#define C_    80
#define HW_   (H_*W_)            // 15200
#define PER_IMG  (A_*C_*HW_)     // 10944000
#define PER_IMG4 (PER_IMG/4)     // 2736000
#define NBIN  2048
#define BIGB_CAP 24576
#define BIGA_CAP 4096
#define SORTN 2048
#define FASTN 1024
#define NDEC  256
#define THRB 2.0f
#define THRA 3.65f
#define CLIPV 4.135166556742356f  // log(1000/16)

#define TPB      256
#define F4_PER_T 8
#define CHUNK    (TPB*F4_PER_T)                       // 2048 float4
#define NB_SCAN  ((PER_IMG4 + CHUNK - 1) / CHUNK)     // 1336
#define LCAPB 256
#define LCAPA 64

// ws layout (bytes):
#define OFF_CNTA 0                                // 2 u32
#define OFF_CNTB 8                                // 2 u32
#define OFF_SORT 256                              // 2 x 1024 x u64 = 16KB
#define OFF_BIGA (256 + 16384)                    // 2 x 4096 x u64 = 64KB
#define OFF_BIGB (256 + 16384 + 65536)            // 2 x 24576 x float2

typedef unsigned long long u64;

__global__ __launch_bounds__(TPB) void scan_kernel(
    const float* __restrict__ cls,
    unsigned int* __restrict__ cntA,
    unsigned int* __restrict__ cntB,
    u64* __restrict__ bigA,
    float2* __restrict__ bigB) {
  const int n = blockIdx.y;
  const float4* __restrict__ in = reinterpret_cast<const float4*>(cls) + (size_t)n * PER_IMG4;
  __shared__ unsigned int lcntA, lcntB, lbaseA, lbaseB;
  __shared__ u64          lkA[LCAPA];
  __shared__ float        lxB[LCAPB]; __shared__ unsigned int liB[LCAPB];
  if (threadIdx.x == 0) { lcntA = 0; lcntB = 0; }
  __syncthreads();

  const int base = blockIdx.x * CHUNK + threadIdx.x;
  float4 v[F4_PER_T];
  int    t[F4_PER_T];
#pragma unroll
  for (int j = 0; j < F4_PER_T; ++j) {
    t[j] = base + j * TPB;
    v[j] = (t[j] < PER_IMG4) ? in[t[j]]
                             : make_float4(-100.f, -100.f, -100.f, -100.f);
  }
#pragma unroll
  for (int j = 0; j < F4_PER_T; ++j) {
    const float4 vv = v[j];
    const float mx = fmaxf(fmaxf(vv.x, vv.y), fmaxf(vv.z, vv.w));
    if (mx > THRB) {
      // rare path (~1.5% of quads): index math + LDS staging
      const int f0  = t[j] * 4;
      const int ac  = f0 / HW_;
      const int rem = f0 - ac * HW_;
      const int h   = rem / W_;
      const int w0  = rem - h * W_;
      const int a   = ac / C_;
      const int c   = ac - a * C_;
      const int idx0 = ((h * W_ + w0) * A_ + a) * C_ + c;   // +720 per elem
      const float xs[4] = {vv.x, vv.y, vv.z, vv.w};
#pragma unroll
      for (int e = 0; e < 4; ++e) {
        const float x = xs[e];
        if (x > THRB) {
          const unsigned idx = (unsigned)(idx0 + e * 720);
          unsigned pos = atomicAdd(&lcntB, 1u);
          if (pos < LCAPB) { lxB[pos] = x; liB[pos] = idx; }
          if (x > THRA) {
            float s = 1.0f / (1.0f + expf(-x));   // key score
            unsigned pa = atomicAdd(&lcntA, 1u);
            if (pa < LCAPA)
              lkA[pa] = ((u64)__float_as_uint(s) << 32) |
                        (u64)(0xFFFFFFFFu - idx);
          }
        }
      }
    }
  }
  __syncthreads();
  if (threadIdx.x == 0) {
    unsigned cA = lcntA; if (cA > LCAPA) cA = LCAPA;
    unsigned cB = lcntB; if (cB > LCAPB) cB = LCAPB;
    lbaseA = cA ? atomicAdd(&cntA[n], cA) : 0u;
    lbaseB = cB ? atomicAdd(&cntB[n], cB) : 0u;
    lcntA = cA; lcntB = cB;
  }
  __syncthreads();
  const unsigned cA = lcntA, cB = lcntB;
  if (threadIdx.x < cA) {
    unsigned pos = lbaseA + threadIdx.x;
    if (pos < BIGA_CAP)
      bigA[(size_t)n * BIGA_CAP + pos] = lkA[threadIdx.x];
  }
  for (unsigned e = threadIdx.x; e < cB; e += TPB) {
    unsigned pos = lbaseB + e;
    if (pos < BIGB_CAP)
      bigB[(size_t)n * BIGB_CAP + pos] = make_float2(lxB[e], __uint_as_float(liB[e]));
  }
}

// 32 blocks per image; block b ranks keys [b*32, b*32+32).
__global__ __launch_bounds__(256) void rank_kernel(
    const unsigned int* __restrict__ cntA,
    const u64* __restrict__ bigA,
    u64* __restrict__ sorted) {
  const int n = blockIdx.x >> 5;
  const int b = blockIdx.x & 31;
  const int tid = threadIdx.x;
  __shared__ u64 skl[FASTN];

  int ca = (int)cntA[n]; if (ca > FASTN) ca = FASTN;
#pragma unroll
  for (int r = 0; r < 4; ++r) {
    int j = tid + r * 256;
    skl[j] = (j < ca) ? bigA[(size_t)n * BIGA_CAP + j] : 0ull;
  }
  __syncthreads();

  const int kidx = b * 32 + (tid >> 3);
  const int sub  = tid & 7;
  const u64 ki = skl[kidx];
  int rank = 0;
#pragma unroll 8
  for (int it = 0; it < 128; ++it) {
    int j = sub + it * 8;                 // stride-8: banks distinct, no conflict
    u64 kj = skl[j];
    rank += (int)((kj > ki) | ((kj == ki) & (j < kidx)));
  }
  rank += __shfl_xor(rank, 1);
  rank += __shfl_xor(rank, 2);
  rank += __shfl_xor(rank, 4);
  if (sub == 0) sorted[(size_t)n * FASTN + rank] = ki;
}

__device__ __forceinline__ void decode_store(
    int s, int idx, float sc, int n,
    const float* __restrict__ reg, const float* __restrict__ anchors,
    float* sx1, float* sy1, float* sx2, float* sy2, float* sar, float* ssc,
    float4* sbx, unsigned short* slab) {
  int c   = idx % C_;
  int loc = idx / C_;
  int a   = loc % A_;
  int hw  = loc / A_;
  int hh  = hw / W_;
  int ww  = hw - hh * W_;
  int rb  = ((n * A_ + a) * 4) * HW_ + hh * W_ + ww;
  float r0 = reg[rb], r1 = reg[rb + HW_], r2 = reg[rb + 2*HW_], r3 = reg[rb + 3*HW_];
  float4 an = reinterpret_cast<const float4*>(anchors)[loc];
  float wdt = an.z - an.x + 1.0f, hgt = an.w - an.y + 1.0f;
  float cx  = an.x + 0.5f * wdt, cy = an.y + 0.5f * hgt;
  float dx = r0 / 10.0f, dy = r1 / 10.0f;
  float dw = fminf(r2 / 5.0f, CLIPV), dh = fminf(r3 / 5.0f, CLIPV);
  float pcx = dx * wdt + cx, pcy = dy * hgt + cy;
  float pw = expf(dw) * wdt, ph = expf(dh) * hgt;
  float x1 = pcx - 0.5f * pw, y1 = pcy - 0.5f * ph;
  float x2 = pcx + 0.5f * pw - 1.0f, y2 = pcy + 0.5f * ph - 1.0f;
  x1 = fminf(fmaxf(x1, 0.0f), (float)(W_*8) - 1.0f);
  y1 = fminf(fmaxf(y1, 0.0f), (float)(H_*8) - 1.0f);
  x2 = fminf(fmaxf(x2, 0.0f), (float)(W_*8) - 1.0f);
  y2 = fminf(fmaxf(y2, 0.0f), (float)(H_*8) - 1.0f);
  bool valid = sc > 0.0f;
  if ((x2 - x1 + 1.0f < 0.0f) || (y2 - y1 + 1.0f < 0.0f)) valid = false;
  int   label = c + 1;
  float off = (float)label * 4096.0f;
  // offset boxes in f32 (replicates reference rounding at large magnitude)
  float ox1 = x1 + off, oy1 = y1 + off, ox2 = x2 + off, oy2 = y2 + off;
  sx1[s] = ox1; sy1[s] = oy1; sx2[s] = ox2; sy2[s] = oy2;
  sar[s] = (ox2 - ox1 + 1.0f) * (oy2 - oy1 + 1.0f);
  sbx[s] = make_float4(x1, y1, x2, y2);
  slab[s] = (unsigned short)label;
  ssc[s] = valid ? sc : -1.0f;
}

__global__ __launch_bounds__(1024) void finish_kernel(
    const unsigned int* __restrict__ cntA,
    const unsigned int* __restrict__ cntB,
    const u64* __restrict__ sorted,
    const float2* __restrict__ bigB,
    const float* __restrict__ reg, const float* __restrict__ anchors,
    float* __restrict__ out) {
  const int n = blockIdx.x;
  const int tid = threadIdx.x;
  const int lane = tid & 63;

  __shared__ u64 skey[SORTN];                    // fallback
  __shared__ unsigned int shist[NBIN];           // fallback
  __shared__ unsigned int csum[256];             // fallback
  __shared__ int s_fb, s_k, s_cut, s_cnt;
  __shared__ float sx1[1000], sy1[1000], sx2[1000], sy2[1000], sar[1000], ssc[1000];
  __shared__ float4 sbx[1000];
  __shared__ unsigned short slab[1000];
  __shared__ int keptidx[100];
  __shared__ unsigned char skeep[1000];          // fallback

  if (tid == 0) { s_cnt = 0; }
  const int caRaw = (int)cntA[n];
  if (tid == 0) s_fb = (caRaw > FASTN || caRaw < NDEC) ? 1 : 0;

  // ---- fast path: decode top-NDEC of the pre-sorted keys ----
  if (tid < NDEC && caRaw >= NDEC && caRaw <= FASTN) {
    u64 key = sorted[(size_t)n * FASTN + tid];
    int idx = (int)(0xFFFFFFFFu - (unsigned)(key & 0xFFFFFFFFu));
    float sc = __uint_as_float((unsigned)(key >> 32));
    decode_store(tid, idx, sc, n, reg, anchors, sx1, sy1, sx2, sy2, sar, ssc, sbx, slab);
  }
  __syncthreads();

  if (s_fb == 0) {
    // ---- single-wave NMS over top NDEC, early-exit at 100 keeps ----
    if (tid < 64) {
      float ka_x1 = 0, ka_y1 = 0, ka_x2 = 0, ka_y2 = 0, ka_ar = 0;
      float kb_x1 = 0, kb_y1 = 0, kb_x2 = 0, kb_y2 = 0, kb_ar = 0;
      int k = 0;
      for (int i = 0; i < NDEC; ++i) {
        if (k >= 100) break;
        float sc = ssc[i];
        float x1 = sx1[i], y1 = sy1[i], x2 = sx2[i], y2 = sy2[i], ar = sar[i];
        bool sup = false;
        if (lane < k) {
          float iw = fminf(x2, ka_x2) - fmaxf(x1, ka_x1) + 1.0f;
          float ih = fminf(y2, ka_y2) - fmaxf(y1, ka_y1) + 1.0f;
          if (iw > 0.0f && ih > 0.0f) {
            float inter = iw * ih;
            sup = inter / (ar + ka_ar - inter) > 0.5f;
          }
        }
        if (lane + 64 < k) {
          float iw = fminf(x2, kb_x2) - fmaxf(x1, kb_x1) + 1.0f;
          float ih = fminf(y2, kb_y2) - fmaxf(y1, kb_y1) + 1.0f;
          if (iw > 0.0f && ih > 0.0f) {
            float inter = iw * ih;
            sup = sup || (inter / (ar + kb_ar - inter) > 0.5f);
          }
        }
        bool any = __any(sup);
        if ((sc > 0.0f) && !any) {
          if (lane == k)      { ka_x1 = x1; ka_y1 = y1; ka_x2 = x2; ka_y2 = y2; ka_ar = ar; }
          if (lane == k - 64) { kb_x1 = x1; kb_y1 = y1; kb_x2 = x2; kb_y2 = y2; kb_ar = ar; }
          if (lane == 0) keptidx[k] = i;
          ++k;
        }
      }
      if (lane == 0) {
        s_k = k;
        if (k < 100) s_fb = 1;   // insufficient keeps in decoded head
      }
    }
    __syncthreads();

    if (s_fb == 0) {
      if (tid < 100) {
        int f = keptidx[tid];
        float4 b = sbx[f];
        int ob = (n * 100 + tid) * 4;
        out[ob + 0] = b.x; out[ob + 1] = b.y; out[ob + 2] = b.z; out[ob + 3] = b.w;
        out[800  + n * 100 + tid] = ssc[f];
        out[1000 + n * 100 + tid] = (float)slab[f];
      }
      return;
    }
  }
  __syncthreads();

  // ================= fallback: full path over list B (never taken) =========
  shist[tid] = 0; shist[tid + 1024] = 0;
  __syncthreads();
  int bigc = (int)cntB[n]; if (bigc > BIGB_CAP) bigc = BIGB_CAP;
  const float2* __restrict__ bn = bigB + (size_t)n * BIGB_CAP;
  for (int e = tid; e < bigc; e += 1024) {
    float x = bn[e].x;
    int b = (int)((x - THRB) * 256.0f); if (b > NBIN - 1) b = NBIN - 1;
    atomicAdd(&shist[b], 1u);
  }
  __syncthreads();
  if (tid < 256) {
    unsigned int s = 0;
    for (int b = tid * 8; b < tid * 8 + 8; ++b) s += shist[b];
    csum[tid] = s;
  }
  __syncthreads();
  if (tid == 0) {
    int acc = 0, cut = 0;
    for (int cch = 255; cch >= 0; --cch) {
      int nacc = acc + (int)csum[cch];
      if (nacc >= 1000) {
        int a = acc;
        for (int b = cch * 8 + 7; b >= cch * 8; --b) { a += (int)shist[b]; if (a >= 1000) { cut = b; break; } }
        break;
      }
      acc = nacc;
    }
    s_cut = cut;
  }
  __syncthreads();
  const int cut = s_cut;
  for (int e = tid; e < bigc; e += 1024) {
    float2 v = bn[e];
    float x = v.x;
    int b = (int)((x - THRB) * 256.0f); if (b > NBIN - 1) b = NBIN - 1;
    if (b >= cut) {
      float s = 1.0f / (1.0f + expf(-x));
      int pos = atomicAdd(&s_cnt, 1);
      if (pos < SORTN)
        skey[pos] = ((u64)__float_as_uint(s) << 32) |
                    (u64)(0xFFFFFFFFu - __float_as_uint(v.y));
    }
  }
  __syncthreads();
  int cnt = s_cnt; if (cnt > SORTN) cnt = SORTN;
  for (int p = tid; p < SORTN; p += 1024)
    if (p >= cnt) skey[p] = 0ull;
  __syncthreads();
  for (int k = 2; k <= SORTN; k <<= 1) {
    for (int j = k >> 1; j > 0; j >>= 1) {
#pragma unroll
      for (int u = 0; u < 2; ++u) {
        int tt = tid + u * 1024;
        int ixj = tt ^ j;
        if (ixj > tt) {
          u64 va = skey[tt], vb = skey[ixj];
          bool asc = ((tt & k) == 0);
          if (asc ? (va > vb) : (va < vb)) { skey[tt] = vb; skey[ixj] = va; }
        }
      }
      __syncthreads();
    }
  }
  if (tid < 1000) {
    u64 key = skey[SORTN - 1 - tid];
    bool ok = (tid < cnt) && (key != 0ull);
    int   idx = ok ? (int)(0xFFFFFFFFu - (unsigned)(key & 0xFFFFFFFFu)) : 0;
    float sc  = ok ? __uint_as_float((unsigned)(key >> 32)) : -1.0f;
    decode_store(tid, idx, sc, n, reg, anchors, sx1, sy1, sx2, sy2, sar, ssc, sbx, slab);
  }
  __syncthreads();
  if (tid < 64) {
    float ka_x1 = 0, ka_y1 = 0, ka_x2 = 0, ka_y2 = 0, ka_ar = 0;
    float kb_x1 = 0, kb_y1 = 0, kb_x2 = 0, kb_y2 = 0, kb_ar = 0;
    int k = 0;
    for (int i = 0; i < 1000; ++i) {
      if (k >= 100) break;
      float sc = ssc[i];
      float x1 = sx1[i], y1 = sy1[i], x2 = sx2[i], y2 = sy2[i], ar = sar[i];
      bool sup = false;
      if (lane < k) {
        float iw = fminf(x2, ka_x2) - fmaxf(x1, ka_x1) + 1.0f;
        float ih = fminf(y2, ka_y2) - fmaxf(y1, ka_y1) + 1.0f;
        if (iw > 0.0f && ih > 0.0f) {
          float inter = iw * ih;
          sup = inter / (ar + ka_ar - inter) > 0.5f;
        }
      }
      if (lane + 64 < k) {
        float iw = fminf(x2, kb_x2) - fmaxf(x1, kb_x1) + 1.0f;
        float ih = fminf(y2, kb_y2) - fmaxf(y1, kb_y1) + 1.0f;
        if (iw > 0.0f && ih > 0.0f) {
          float inter = iw * ih;
          sup = sup || (inter / (ar + kb_ar - inter) > 0.5f);
        }
      }
      bool any = __any(sup);
      bool valid = sc > 0.0f;
      if (valid && !any) {
        if (lane == k)      { ka_x1 = x1; ka_y1 = y1; ka_x2 = x2; ka_y2 = y2; ka_ar = ar; }
        if (lane == k - 64) { kb_x1 = x1; kb_y1 = y1; kb_x2 = x2; kb_y2 = y2; kb_ar = ar; }
        if (lane == 0) { keptidx[k] = i; skeep[i] = 1; }
        ++k;
      } else if (lane == 0) {
        skeep[i] = 0;
      }
    }
    if (lane == 0) {
      if (k < 100) {
        int fill = k;
        for (int q = 0; q < 1000 && fill < 100; ++q)
          if (!skeep[q]) keptidx[fill++] = q;
      }
      s_k = k;
    }
  }
  __syncthreads();
  if (tid < 100) {
    int f = keptidx[tid];
    bool isk = tid < s_k;
    float4 b = sbx[f];
    float sc  = isk ? ssc[f] : -1.0f;
    float lab = (sc > 0.0f) ? (float)slab[f] : 0.0f;
    int ob = (n * 100 + tid) * 4;
    out[ob + 0] = b.x; out[ob + 1] = b.y; out[ob + 2] = b.z; out[ob + 3] = b.w;
    out[800  + n * 100 + tid] = sc;
    out[1000 + n * 100 + tid] = lab;
  }
}

extern "C" void kernel_launch(void* const* d_in, const int* in_sizes, int n_in,
                              void* d_out, int out_size, void* d_ws, size_t ws_size,
                              hipStream_t stream) {
  const float* cls = (const float*)d_in[0];
  const float* reg = (const float*)d_in[1];
  const float* anc = (const float*)d_in[2];
  float* out = (float*)d_out;
  char* ws = (char*)d_ws;
  unsigned int* cntA = (unsigned int*)(ws + OFF_CNTA);
  unsigned int* cntB = (unsigned int*)(ws + OFF_CNTB);
  u64*    sorted     = (u64*)(ws + OFF_SORT);
  u64*    bigA       = (u64*)(ws + OFF_BIGA);
  float2* bigB       = (float2*)(ws + OFF_BIGB);

  hipMemsetAsync(d_ws, 0, 16, stream);
  dim3 g1(NB_SCAN, 2);
  scan_kernel<<<g1, TPB, 0, stream>>>(cls, cntA, cntB, bigA, bigB);
  rank_kernel<<<64, 256, 0, stream>>>(cntA, bigA, sorted);
  finish_kernel<<<2, 1024, 0, stream>>>(cntA, cntB, sorted, bigB, reg, anc, out);
}